// Round 2
// baseline (4245.078 us; speedup 1.0000x reference)
//
#include <hip/hip_runtime.h>

// LSTM B=64, S=512, D=H=512 — persistent kernel, XCD-local groups.
//  - 256 WGs = 8 batch-groups (8 rows) x 32 h-slices (16 h-cols = 64 gate cols)
//  - group = bid & 7  -> all 32 WGs of a group on ONE XCD (bid%8 round-robin),
//    so h-exchange + counter atomics stay in that XCD's L2.
//  - Per WG: B = [W;U] slice (1024 x 64 gate cols) bf16 resident in LDS (128 KB,
//    col-major, per-col XOR swizzle). A = 8 rows x 512 bf16 (8 KB), staged per
//    step (x_t, then h_{t-1}); gates exchange aliases A region.

#define NG   8
#define GR   8
#define NS   32
#define SC   16
#define DIM  512
#define HID  512
#define SEQ  512
#define NTHR 256
#define NWG  (NG*NS)

#define AOFF 0
#define BOFF (GR*1024)                 // A region: 8 rows x 512 bf16 = 8 KB
#define LDS_BYTES (BOFF + 64*2048)     // + B region 128 KB = 139264

#define WS_CNT_BYTES 1024
#define HBUF_ELEMS   (2*NG*GR*HID)     // 2 parities x 64 rows x 512
#define WS_NEED      (WS_CNT_BYTES + HBUF_ELEMS*2)

typedef float f32x4  __attribute__((ext_vector_type(4)));
typedef short bf16x8 __attribute__((ext_vector_type(8)));

__device__ __forceinline__ unsigned short f2bf(float f){
  union { float f; unsigned u; } v; v.f = f;
  unsigned r = v.u + 0x7fffu + ((v.u >> 16) & 1u);   // RNE
  return (unsigned short)(r >> 16);
}
__device__ __forceinline__ float sigm(float x){ return 1.0f/(1.0f + __expf(-x)); }
__device__ __forceinline__ float tanh_f(float x){
  float e = __expf(-2.0f * fabsf(x));
  float t = (1.0f - e)/(1.0f + e);
  return x < 0.0f ? -t : t;
}

__global__ void zero_ws_kernel(uint4* p, int n4){
  int i = blockIdx.x*blockDim.x + threadIdx.x;
  uint4 z; z.x=0u; z.y=0u; z.z=0u; z.w=0u;
  if (i < n4) p[i] = z;
}

__global__ __launch_bounds__(NTHR, 1) void lstm_persistent(
  const float* __restrict__ x,
  const float* __restrict__ W0, const float* __restrict__ W1,
  const float* __restrict__ W2, const float* __restrict__ W3,
  const float* __restrict__ U0, const float* __restrict__ U1,
  const float* __restrict__ U2, const float* __restrict__ U3,
  const float* __restrict__ b0, const float* __restrict__ b1,
  const float* __restrict__ b2, const float* __restrict__ b3,
  float* __restrict__ out,
  unsigned* __restrict__ cnt,
  unsigned short* __restrict__ hbuf)
{
  __shared__ __align__(16) char smem[LDS_BYTES];
  const int tid = threadIdx.x;
  const int bid = blockIdx.x;
  const int g = bid & 7;        // batch group -> XCD (bid%8 round-robin)
  const int s = bid >> 3;       // h-slice 0..31 (h cols 16s..16s+15)
  const int w = tid >> 6;       // wave = gate (i,f,o,c)
  const int l = tid & 63;

  // ---- one-time: stage B = [W;U] slice into LDS, COALESCED global reads ----
  // thread t: q = t&3 (16B chunk of a 64B row segment), kk = t>>2 (k row 0..63)
  {
    const int q  = tid & 3;
    const int kk = tid >> 2;
    for (int gate = 0; gate < 4; ++gate){
      const float* Wsrc = (gate==0)?W0:(gate==1)?W1:(gate==2)?W2:W3;
      const float* Usrc = (gate==0)?U0:(gate==1)?U1:(gate==2)?U2:U3;
      #pragma unroll
      for (int kb = 0; kb < 16; ++kb){
        const int k = kb*64 + kk;                       // 0..1023 over [W;U]
        const float* p = (k < DIM)
          ? (Wsrc + (size_t)k*HID + s*SC + q*4)
          : (Usrc + (size_t)(k-DIM)*HID + s*SC + q*4);
        f32x4 v = *(const f32x4*)p;
        #pragma unroll
        for (int j = 0; j < 4; ++j){
          const int c = gate*16 + q*4 + j;              // local gate col 0..63
          const unsigned byte = ((unsigned)(k*2)) ^ ((unsigned)((c&7)<<4));
          *(unsigned short*)(&smem[BOFF + c*2048] + byte) = f2bf(v[j]);
        }
      }
    }
  }

  // elementwise mapping: tid<128 -> (row er 0..7, col ec 0..15)
  const int er = tid >> 4;          // 0..15, valid only <8 (tid<128)
  const int ec = tid & 15;
  const int ecol = s*SC + ec;
  const bool ew = (tid < 128);
  const float bi  = ew ? b0[ecol] : 0.f;
  const float bff = ew ? b1[ecol] : 0.f;
  const float bo  = ew ? b2[ecol] : 0.f;
  const float bc  = ew ? b3[ecol] : 0.f;
  float cstate = 0.0f, hout = 0.0f;

  // MFMA fragment constants
  const int arow = l & 15;
  const int qh   = l >> 4;
  const unsigned swz = (unsigned)((arow & 7) << 4);     // (w*16+arow)&7 == arow&7
  const char* Abase = &smem[AOFF + (arow & 7)*1024];    // rows 8-15 duplicate 0-7
  const char* Bbase = &smem[BOFF + (w*16 + arow)*2048];
  float* gatesLds = (float*)&smem[AOFF];                // alias, post-GEMM only

  // staging mapping: thread -> (row sr 0..7, chunk sc16 0..31 of 16 elems)
  const int sr   = tid >> 5;
  const int sc16 = tid & 31;
  const unsigned swzS = (unsigned)((sr & 7) << 4);
  char* Arow = &smem[AOFF + sr*1024];

  unsigned* mycnt = &cnt[g*32];

  __syncthreads();

#define GEMM_STEP(QA, QB, ACC) do { \
    bf16x8 a_ = *(const bf16x8*)(Abase + (((unsigned)((QA)*64 + qh*16)) ^ swz)); \
    bf16x8 b_ = *(const bf16x8*)(Bbase + (((unsigned)((QB)*64 + qh*16)) ^ swz)); \
    ACC = __builtin_amdgcn_mfma_f32_16x16x32_bf16(a_, b_, ACC, 0, 0, 0); \
  } while(0)

  for (int t = 0; t < SEQ; ++t){
    // 1) stage x[g-rows, t, :] -> A (fp32->bf16): row sr, 16 floats per thread
    {
      const float* xp = x + ((size_t)(g*GR + sr)*SEQ + (size_t)t)*DIM + sc16*16;
      f32x4 u0 = *(const f32x4*)(xp + 0);
      f32x4 u1 = *(const f32x4*)(xp + 4);
      f32x4 u2 = *(const f32x4*)(xp + 8);
      f32x4 u3 = *(const f32x4*)(xp + 12);
      bf16x8 o0, o1;
      o0[0]=(short)f2bf(u0[0]); o0[1]=(short)f2bf(u0[1]);
      o0[2]=(short)f2bf(u0[2]); o0[3]=(short)f2bf(u0[3]);
      o0[4]=(short)f2bf(u1[0]); o0[5]=(short)f2bf(u1[1]);
      o0[6]=(short)f2bf(u1[2]); o0[7]=(short)f2bf(u1[3]);
      o1[0]=(short)f2bf(u2[0]); o1[1]=(short)f2bf(u2[1]);
      o1[2]=(short)f2bf(u2[2]); o1[3]=(short)f2bf(u2[3]);
      o1[4]=(short)f2bf(u3[0]); o1[5]=(short)f2bf(u3[1]);
      o1[6]=(short)f2bf(u3[2]); o1[7]=(short)f2bf(u3[3]);
      *(bf16x8*)(Arow + (((unsigned)(sc16*32 +  0)) ^ swzS)) = o0;
      *(bf16x8*)(Arow + (((unsigned)(sc16*32 + 16)) ^ swzS)) = o1;
    }
    __syncthreads();                                   // bar1

    f32x4 acc0 = {0.f,0.f,0.f,0.f}, acc1 = {0.f,0.f,0.f,0.f};
    f32x4 acc2 = {0.f,0.f,0.f,0.f}, acc3 = {0.f,0.f,0.f,0.f};

    // 2) x-half GEMM (B rows 0..511 = W), K=512 -> 16 MFMA
    #pragma unroll
    for (int q4 = 0; q4 < 4; ++q4){
      GEMM_STEP(q4*4+0, q4*4+0, acc0);
      GEMM_STEP(q4*4+1, q4*4+1, acc1);
      GEMM_STEP(q4*4+2, q4*4+2, acc2);
      GEMM_STEP(q4*4+3, q4*4+3, acc3);
    }

    // 3) wait for the 32 producers of h_{t-1} (in-XCD L2 spin)
    if (t > 0 && tid == 0){
      const unsigned target = (unsigned)(32*t);
      while (__hip_atomic_load(mycnt, __ATOMIC_ACQUIRE, __HIP_MEMORY_SCOPE_AGENT) < target)
        __builtin_amdgcn_s_sleep(1);
    }
    __syncthreads();                                   // bar2

    // 4) stage h_{t-1} -> A (bf16 passthrough)
    {
      const unsigned short* hsrc =
        hbuf + ((size_t)((t&1)*NG + g)*GR + sr)*HID + sc16*16;
      bf16x8 h0 = *(const bf16x8*)(hsrc + 0);
      bf16x8 h1 = *(const bf16x8*)(hsrc + 8);
      *(bf16x8*)(Arow + (((unsigned)(sc16*32 +  0)) ^ swzS)) = h0;
      *(bf16x8*)(Arow + (((unsigned)(sc16*32 + 16)) ^ swzS)) = h1;
    }
    __syncthreads();                                   // bar3

    // 5) h-half GEMM (B rows 512..1023 = U)
    #pragma unroll
    for (int q4 = 0; q4 < 4; ++q4){
      GEMM_STEP(q4*4+0, q4*4+16, acc0);
      GEMM_STEP(q4*4+1, q4*4+17, acc1);
      GEMM_STEP(q4*4+2, q4*4+18, acc2);
      GEMM_STEP(q4*4+3, q4*4+19, acc3);
    }
    __syncthreads();                                   // bar4: A consumed

    // 6) gate exchange (C/D: col=l&15, row=4*qh+rr; rows 0..7 only)
    f32x4 accs = (acc0 + acc1) + (acc2 + acc3);
    if (qh < 2){
      #pragma unroll
      for (int rr = 0; rr < 4; ++rr)
        gatesLds[(qh*4 + rr)*64 + w*16 + arow] = accs[rr];
    }
    __syncthreads();                                   // bar5

    // 7) elementwise LSTM cell, fp32 state (tid<128)
    if (ew){
      float gi = gatesLds[er*64 +  0 + ec] + bi;
      float gf = gatesLds[er*64 + 16 + ec] + bff;
      float go = gatesLds[er*64 + 32 + ec] + bo;
      float gc = gatesLds[er*64 + 48 + ec] + bc;
      float ig = sigm(gi), fg = sigm(gf), og = sigm(go), ct = tanh_f(gc);
      cstate = fg*cstate + ig*ct;
      hout = og * tanh_f(cstate);
      hbuf[((size_t)(((t+1)&1)*NG + g)*GR + er)*HID + s*SC + ec] = f2bf(hout);
    }
    __syncthreads();                                   // bar6

    // 8) release: bump group counter (h stores ordered by bar6 + release)
    if (tid == 0)
      __hip_atomic_fetch_add(mycnt, 1u, __ATOMIC_RELEASE, __HIP_MEMORY_SCOPE_AGENT);
  }

  if (ew)
    out[(size_t)(g*GR + er)*HID + s*SC + ec] = hout;
#undef GEMM_STEP
}

extern "C" void kernel_launch(void* const* d_in, const int* in_sizes, int n_in,
                              void* d_out, int out_size, void* d_ws, size_t ws_size,
                              hipStream_t stream)
{
  (void)in_sizes; (void)n_in; (void)out_size;
  if (ws_size < (size_t)WS_NEED) return;

  const float* x  = (const float*)d_in[0];
  const float* W0 = (const float*)d_in[1];
  const float* W1 = (const float*)d_in[2];
  const float* W2 = (const float*)d_in[3];
  const float* W3 = (const float*)d_in[4];
  const float* U0 = (const float*)d_in[5];
  const float* U1 = (const float*)d_in[6];
  const float* U2 = (const float*)d_in[7];
  const float* U3 = (const float*)d_in[8];
  const float* b0 = (const float*)d_in[9];
  const float* b1 = (const float*)d_in[10];
  const float* b2 = (const float*)d_in[11];
  const float* b3 = (const float*)d_in[12];
  float* out = (float*)d_out;

  unsigned* cnt = (unsigned*)d_ws;
  unsigned short* hbuf = (unsigned short*)((char*)d_ws + WS_CNT_BYTES);

  const int n4 = WS_NEED / 16;
  zero_ws_kernel<<<dim3((n4 + 255)/256), dim3(256), 0, stream>>>((uint4*)d_ws, n4);
  lstm_persistent<<<dim3(NWG), dim3(NTHR), 0, stream>>>(
      x, W0,W1,W2,W3, U0,U1,U2,U3, b0,b1,b2,b3, out, cnt, hbuf);
}